// Round 1
// baseline (286.878 us; speedup 1.0000x reference)
//
#include <hip/hip_runtime.h>
#include <math.h>

#define Bb   16
#define HWn  4096
#define Ff   512
#define Kk   32
#define TM   32
#define CHUNK 256
#define TILES (CHUNK / TM)

// workspace layout (float offsets)
#define WS_ENC   0
#define WS_SSUM  (Bb * Kk * Ff)            // 262144
#define WS_EOUT  (WS_SSUM + Bb * Kk)       // 262656
#define WS_ATTN  (WS_EOUT + Bb * Ff)       // 270848

// ---------------------------------------------------------------------------
// Kernel A: fused encoder pass.
// grid (HWn/CHUNK, Bb), block 256. Each block: one b, 256 rows (8 tiles of 32).
// Produces enc_acc[b][k][f] = sum_n s[n][k]*x[n][f]  (atomicAdd)
//          s_sum[b][k]      = sum_n s[n][k]          (atomicAdd)
// ---------------------------------------------------------------------------
__global__ __launch_bounds__(256, 1) void enc_pass(
    const float* __restrict__ x, const float* __restrict__ cw,
    const float* __restrict__ smth, float* __restrict__ enc_acc,
    float* __restrict__ s_sum)
{
    __shared__ float cw_t[Ff][Kk];          // 64 KB, [f][k]
    __shared__ float ftile[TM][Ff + 4];     // 66 KB, +4 pad (row stride 516, 16B aligned)
    __shared__ float part[4][TM][Kk + 4];   // 18 KB, phase-1 f-split partials
    __shared__ float s_tile[TM][Kk];        // 4 KB
    __shared__ float x2s[TM];
    __shared__ float c2s[Kk];
    __shared__ float sms[Kk];

    const int tid  = threadIdx.x;
    const int b    = blockIdx.y;
    const int row0 = blockIdx.x * CHUNK;

    // stage codewords transposed: thread -> k = tid&31, 64-f slab = tid>>5
    {
        const int k  = tid & 31;
        const int fo = (tid >> 5) << 6;
        #pragma unroll
        for (int i = 0; i < 16; ++i) {
            const float4 v = *reinterpret_cast<const float4*>(&cw[k * Ff + fo + i * 4]);
            cw_t[fo + i * 4 + 0][k] = v.x;
            cw_t[fo + i * 4 + 1][k] = v.y;
            cw_t[fo + i * 4 + 2][k] = v.z;
            cw_t[fo + i * 4 + 3][k] = v.w;
        }
        if (tid < Kk) sms[tid] = smth[tid];
    }
    __syncthreads();
    if (tid < Kk) {                          // c2[k] = ||cw_k||^2
        float a = 0.f;
        for (int f = 0; f < Ff; ++f) { const float c = cw_t[f][tid]; a = fmaf(c, c, a); }
        c2s[tid] = a;
    }

    // phase-2 accumulators: thread owns k-quad kg2 and 16 f (fslot*4 + j*128)
    float4 acc[4][4];
    #pragma unroll
    for (int i1 = 0; i1 < 4; ++i1)
        #pragma unroll
        for (int i2 = 0; i2 < 4; ++i2) acc[i1][i2] = make_float4(0.f, 0.f, 0.f, 0.f);
    float ssum_loc[4] = {0.f, 0.f, 0.f, 0.f};

    const int fs    = tid & 3;          // phase1 f-range (128 f each)
    const int kg    = (tid >> 2) & 7;   // phase1 k-quad
    const int ng    = tid >> 5;         // phase1 row-quad
    const int srow  = tid >> 3;         // softmax/x2 row
    const int sks   = tid & 7;          // softmax k-quad / x2 f-slot
    const int kg2   = tid >> 5;         // phase2 k-quad
    const int fslot = tid & 31;         // phase2 f-slot

    for (int t = 0; t < TILES; ++t) {
        __syncthreads();   // protect ftile from previous phase-2 readers
        // ---- stage feats tile (coalesced float4) ----
        {
            const float* gsrc = x + ((long)b * HWn + row0 + t * TM) * Ff;
            #pragma unroll
            for (int i = 0; i < 16; ++i) {
                const int idx = tid + i * 256;
                const int r   = idx >> 7;
                const int f4  = (idx & 127) << 2;
                *reinterpret_cast<float4*>(&ftile[r][f4]) =
                    *reinterpret_cast<const float4*>(&gsrc[r * Ff + f4]);
            }
        }
        __syncthreads();
        // ---- x2 per row: 8 threads/row ----
        {
            float p = 0.f;
            #pragma unroll
            for (int j = 0; j < 16; ++j) {
                const float4 v = *reinterpret_cast<const float4*>(&ftile[srow][sks * 4 + j * 32]);
                p = fmaf(v.x, v.x, fmaf(v.y, v.y, fmaf(v.z, v.z, fmaf(v.w, v.w, p))));
            }
            p += __shfl_xor(p, 1); p += __shfl_xor(p, 2); p += __shfl_xor(p, 4);
            if (sks == 0) x2s[srow] = p;
        }
        // ---- phase 1: xc partials, 4n x 4k per thread over 128 f ----
        {
            float4 xc[4];
            #pragma unroll
            for (int i = 0; i < 4; ++i) xc[i] = make_float4(0.f, 0.f, 0.f, 0.f);
            #pragma unroll 4
            for (int f4 = 0; f4 < 32; ++f4) {
                const int fb = fs * 128 + f4 * 4;
                float fta[4][4];
                #pragma unroll
                for (int i = 0; i < 4; ++i) {
                    const float4 v = *reinterpret_cast<const float4*>(&ftile[ng * 4 + i][fb]);
                    fta[i][0] = v.x; fta[i][1] = v.y; fta[i][2] = v.z; fta[i][3] = v.w;
                }
                #pragma unroll
                for (int e = 0; e < 4; ++e) {
                    const float4 c = *reinterpret_cast<const float4*>(&cw_t[fb + e][kg * 4]);
                    #pragma unroll
                    for (int i = 0; i < 4; ++i) {
                        xc[i].x = fmaf(fta[i][e], c.x, xc[i].x);
                        xc[i].y = fmaf(fta[i][e], c.y, xc[i].y);
                        xc[i].z = fmaf(fta[i][e], c.z, xc[i].z);
                        xc[i].w = fmaf(fta[i][e], c.w, xc[i].w);
                    }
                }
            }
            #pragma unroll
            for (int i = 0; i < 4; ++i) {
                part[fs][ng * 4 + i][kg * 4 + 0] = xc[i].x;
                part[fs][ng * 4 + i][kg * 4 + 1] = xc[i].y;
                part[fs][ng * 4 + i][kg * 4 + 2] = xc[i].z;
                part[fs][ng * 4 + i][kg * 4 + 3] = xc[i].w;
            }
        }
        __syncthreads();
        // ---- softmax over k (8 threads/row, 4 k each) ----
        {
            float lg[4];
            const float xv = x2s[srow];
            #pragma unroll
            for (int j = 0; j < 4; ++j) {
                const int k = sks * 4 + j;
                const float xc = part[0][srow][k] + part[1][srow][k] +
                                 part[2][srow][k] + part[3][srow][k];
                lg[j] = (xv - 2.f * xc + c2s[k]) * sms[k];
            }
            float mx = fmaxf(fmaxf(lg[0], lg[1]), fmaxf(lg[2], lg[3]));
            mx = fmaxf(mx, __shfl_xor(mx, 1));
            mx = fmaxf(mx, __shfl_xor(mx, 2));
            mx = fmaxf(mx, __shfl_xor(mx, 4));
            float ev[4]; float sm = 0.f;
            #pragma unroll
            for (int j = 0; j < 4; ++j) { ev[j] = expf(lg[j] - mx); sm += ev[j]; }
            sm += __shfl_xor(sm, 1); sm += __shfl_xor(sm, 2); sm += __shfl_xor(sm, 4);
            const float inv = 1.f / sm;
            #pragma unroll
            for (int j = 0; j < 4; ++j) {
                const float sv = ev[j] * inv;
                s_tile[srow][sks * 4 + j] = sv;
                ssum_loc[j] += sv;
            }
        }
        __syncthreads();
        // ---- phase 2: enc_acc += s^T @ ftile (register accumulate) ----
        {
            #pragma unroll 4
            for (int n = 0; n < TM; ++n) {
                const float4 sv = *reinterpret_cast<const float4*>(&s_tile[n][kg2 * 4]);
                const float sk0 = sv.x, sk1 = sv.y, sk2 = sv.z, sk3 = sv.w;
                #pragma unroll
                for (int j = 0; j < 4; ++j) {
                    const float4 fv = *reinterpret_cast<const float4*>(&ftile[n][fslot * 4 + j * 128]);
                    acc[0][j].x = fmaf(sk0, fv.x, acc[0][j].x);
                    acc[0][j].y = fmaf(sk0, fv.y, acc[0][j].y);
                    acc[0][j].z = fmaf(sk0, fv.z, acc[0][j].z);
                    acc[0][j].w = fmaf(sk0, fv.w, acc[0][j].w);
                    acc[1][j].x = fmaf(sk1, fv.x, acc[1][j].x);
                    acc[1][j].y = fmaf(sk1, fv.y, acc[1][j].y);
                    acc[1][j].z = fmaf(sk1, fv.z, acc[1][j].z);
                    acc[1][j].w = fmaf(sk1, fv.w, acc[1][j].w);
                    acc[2][j].x = fmaf(sk2, fv.x, acc[2][j].x);
                    acc[2][j].y = fmaf(sk2, fv.y, acc[2][j].y);
                    acc[2][j].z = fmaf(sk2, fv.z, acc[2][j].z);
                    acc[2][j].w = fmaf(sk2, fv.w, acc[2][j].w);
                    acc[3][j].x = fmaf(sk3, fv.x, acc[3][j].x);
                    acc[3][j].y = fmaf(sk3, fv.y, acc[3][j].y);
                    acc[3][j].z = fmaf(sk3, fv.z, acc[3][j].z);
                    acc[3][j].w = fmaf(sk3, fv.w, acc[3][j].w);
                }
            }
        }
    }
    // ---- s_sum reduce + writeback ----
    __syncthreads();
    #pragma unroll
    for (int j = 0; j < 4; ++j) part[0][srow][sks * 4 + j] = ssum_loc[j];
    __syncthreads();
    if (tid < Kk) {
        float a = 0.f;
        for (int r = 0; r < TM; ++r) a += part[0][r][tid];
        atomicAdd(&s_sum[b * Kk + tid], a);
    }
    // ---- enc_acc writeback ----
    #pragma unroll
    for (int kk = 0; kk < 4; ++kk) {
        const int k = kg2 * 4 + kk;
        #pragma unroll
        for (int j = 0; j < 4; ++j) {
            const int f = fslot * 4 + j * 128;
            float* dst = &enc_acc[((long)b * Kk + k) * Ff + f];
            atomicAdd(dst + 0, acc[kk][j].x);
            atomicAdd(dst + 1, acc[kk][j].y);
            atomicAdd(dst + 2, acc[kk][j].z);
            atomicAdd(dst + 3, acc[kk][j].w);
        }
    }
}

// ---------------------------------------------------------------------------
// Kernel B1: enc = enc_acc - s_sum*cw; BN(inference)+ReLU; sum over k -> enc_out
// also se_loss[b] = enc_out . se_w + se_b.   grid Bb, block 512.
// ---------------------------------------------------------------------------
__global__ void enc_finish(const float* __restrict__ enc_acc,
                           const float* __restrict__ s_sum,
                           const float* __restrict__ cw,
                           const float* __restrict__ gamma,
                           const float* __restrict__ beta,
                           const float* __restrict__ mean,
                           const float* __restrict__ var,
                           const float* __restrict__ se_w,
                           const float* __restrict__ se_b,
                           float* __restrict__ enc_out,
                           float* __restrict__ se_out)
{
    __shared__ float ss[Kk];
    __shared__ float red[8];
    const int b = blockIdx.x, f = threadIdx.x;
    if (f < Kk) ss[f] = s_sum[b * Kk + f];
    __syncthreads();
    const float m  = mean[f];
    const float g  = gamma[f];
    const float bt = beta[f];
    const float iv = rsqrtf(var[f] + 1e-3f);
    float a = 0.f;
    #pragma unroll 4
    for (int k = 0; k < Kk; ++k) {
        float v = enc_acc[((long)b * Kk + k) * Ff + f] - ss[k] * cw[k * Ff + f];
        v = (v - m) * iv * g + bt;
        a += fmaxf(v, 0.f);
    }
    enc_out[b * Ff + f] = a;
    float p = a * se_w[f];
    p += __shfl_down(p, 32); p += __shfl_down(p, 16); p += __shfl_down(p, 8);
    p += __shfl_down(p, 4);  p += __shfl_down(p, 2);  p += __shfl_down(p, 1);
    if ((f & 63) == 0) red[f >> 6] = p;
    __syncthreads();
    if (f == 0) {
        float t = 0.f;
        #pragma unroll
        for (int i = 0; i < 8; ++i) t += red[i];
        se_out[b] = t + se_b[0];
    }
}

// ---------------------------------------------------------------------------
// Kernel B2: attn[b][f] = sigmoid(enc_out[b] . W[:,f] + bias[f]). grid Bb, blk 512.
// ---------------------------------------------------------------------------
__global__ void attn_fc(const float* __restrict__ enc_out,
                        const float* __restrict__ W,
                        const float* __restrict__ bias,
                        float* __restrict__ attn)
{
    __shared__ float eo[Ff];
    const int b = blockIdx.x, f = threadIdx.x;
    eo[f] = enc_out[b * Ff + f];
    __syncthreads();
    float a = bias[f];
    #pragma unroll 8
    for (int fp = 0; fp < Ff; ++fp) a = fmaf(eo[fp], W[fp * Ff + f], a);
    attn[b * Ff + f] = 1.f / (1.f + expf(-a));
}

// ---------------------------------------------------------------------------
// Kernel C: featuremaps = attn (broadcast) * inputs. float4 grid-stride.
// ---------------------------------------------------------------------------
__global__ void bcast_mul(const float4* __restrict__ x4,
                          const float* __restrict__ attn,
                          float4* __restrict__ o4)
{
    const int stride = gridDim.x * blockDim.x;
    const int total4 = Bb * HWn * Ff / 4;   // 8388608
    for (int i = blockIdx.x * blockDim.x + threadIdx.x; i < total4; i += stride) {
        const float4 v = x4[i];
        const int f4 = i & 127;
        const int bb = i >> 19;             // HWn*Ff/4 = 2^19
        const float4 a = *reinterpret_cast<const float4*>(&attn[bb * Ff + f4 * 4]);
        o4[i] = make_float4(v.x * a.x, v.y * a.y, v.z * a.z, v.w * a.w);
    }
}

extern "C" void kernel_launch(void* const* d_in, const int* in_sizes, int n_in,
                              void* d_out, int out_size, void* d_ws, size_t ws_size,
                              hipStream_t stream)
{
    (void)in_sizes; (void)n_in; (void)out_size; (void)ws_size;
    const float* x     = (const float*)d_in[0];
    const float* cw    = (const float*)d_in[1];
    const float* smth  = (const float*)d_in[2];
    const float* gamma = (const float*)d_in[3];
    const float* beta  = (const float*)d_in[4];
    const float* mean  = (const float*)d_in[5];
    const float* var   = (const float*)d_in[6];
    const float* Wenc  = (const float*)d_in[7];
    const float* benc  = (const float*)d_in[8];
    const float* Wse   = (const float*)d_in[9];
    const float* bse   = (const float*)d_in[10];

    float* out = (float*)d_out;
    float* ws  = (float*)d_ws;
    float* enc_acc = ws + WS_ENC;
    float* ssum    = ws + WS_SSUM;
    float* eout    = ws + WS_EOUT;
    float* attn    = ws + WS_ATTN;

    // zero the atomic accumulation regions (enc_acc + s_sum)
    hipMemsetAsync(ws, 0, (size_t)(WS_SSUM + Bb * Kk) * sizeof(float), stream);

    enc_pass<<<dim3(HWn / CHUNK, Bb), 256, 0, stream>>>(x, cw, smth, enc_acc, ssum);
    enc_finish<<<Bb, 512, 0, stream>>>(enc_acc, ssum, cw, gamma, beta, mean, var,
                                       Wse, bse, eout, out + (long)Bb * HWn * Ff);
    attn_fc<<<Bb, 512, 0, stream>>>(eout, Wenc, benc, attn);
    bcast_mul<<<2048, 256, 0, stream>>>((const float4*)x, attn, (float4*)out);
}